// Round 11
// baseline (312.639 us; speedup 1.0000x reference)
//
#include <hip/hip_runtime.h>
#include <hip/hip_bf16.h>
#include <stdint.h>

#define N_NODES 100000
#define DIM 128
#define NREL 4
#define NEDGE 500000
#define M_FLAT (NREL * N_NODES)        // 400000 flat (r,node) slots
#define TOT_E (NREL * NEDGE)           // 2M edges
#define BSLOT 1024                     // flat slots per bucket
#define NBK ((M_FLAT + BSLOT - 1) / BSLOT)   // 391 buckets
#define CAP 8192                       // padded edge capacity per bucket (mean 5120, 43 sigma slack)
#define CHUNK 8192                     // edges per bscatter role-block
#define NBSC ((TOT_E + CHUNK - 1) / CHUNK)            // 245 bscatter blocks
#define NQ (N_NODES * DIM / 4)                        // 3.2M float4 elements for xb
#define XB_BATCH 8
#define NBXB ((NQ + 256 * XB_BATCH - 1) / (256 * XB_BATCH))   // 1563 xb blocks
#define NBPREP ((5 * DIM * DIM + 255) / 256)          // 320 prep blocks

typedef __attribute__((ext_vector_type(8))) short short8;
typedef __attribute__((ext_vector_type(4))) float f32x4;
typedef __attribute__((ext_vector_type(2))) float f32x2;

__device__ __forceinline__ unsigned short f2bf(float f) {
  unsigned int u = __float_as_uint(f);
  u += 0x7fffu + ((u >> 16) & 1u);   // RNE
  return (unsigned short)(u >> 16);
}

// Fused preprocessing, role-split by blockIdx (independent jobs; fusing removes
// two serial dispatches + hides xb/prep under bscatter — R8/R10 measured best).
__global__ __launch_bounds__(256) void pre_kernel(
    const int* __restrict__ src, const int* __restrict__ dst,
    int* __restrict__ bcnt, unsigned int* __restrict__ gpairs,
    const float* __restrict__ x, unsigned short* __restrict__ xb,
    const float* __restrict__ Ws, const float* __restrict__ Wn,
    const float* __restrict__ bv, unsigned short* __restrict__ Wt,
    float* __restrict__ biasc) {
  __shared__ unsigned int buf[CHUNK];
  __shared__ unsigned short barr[CHUNK];
  __shared__ int hist[NBK];
  __shared__ int sbase[NBK];
  __shared__ int lcur[NBK];
  __shared__ int gbase[NBK];
  __shared__ int part[256];
  int bid = blockIdx.x;
  int tid = threadIdx.x;

  if (bid < NBSC) {
    // ---- bscatter role ----
    int base = bid * CHUNK;
    int m = TOT_E - base; if (m > CHUNK) m = CHUNK;
    for (int i = tid; i < NBK; i += 256) { hist[i] = 0; lcur[i] = 0; }
    __syncthreads();
    unsigned int pk[CHUNK / 256];
    int bk[CHUNK / 256];
#pragma unroll
    for (int k = 0; k < CHUNK / 256; ++k) {
      int i = k * 256 + tid;
      int idx = base + i;
      int b = -1; unsigned int p = 0;
      if (i < m) {
        int r = idx / NEDGE;
        int fl = r * N_NODES + dst[idx];
        b = fl >> 10;
        p = ((unsigned int)(fl & (BSLOT - 1)) << 17) | (unsigned int)src[idx];
        atomicAdd(&hist[b], 1);
      }
      pk[k] = p; bk[k] = b;
    }
    __syncthreads();
    // two-pass exclusive scan over hist[0..NBK) (NBK = 391 > 256)
    {
      int vA = hist[tid];
      part[tid] = vA;
      __syncthreads();
      for (int o = 1; o < 256; o <<= 1) {
        int u = (tid >= o) ? part[tid - o] : 0;
        __syncthreads();
        part[tid] += u;
        __syncthreads();
      }
      sbase[tid] = part[tid] - vA;
      int totalA = part[255];
      __syncthreads();
      int vB = (256 + tid < NBK) ? hist[256 + tid] : 0;
      part[tid] = vB;
      __syncthreads();
      for (int o = 1; o < 256; o <<= 1) {
        int u = (tid >= o) ? part[tid - o] : 0;
        __syncthreads();
        part[tid] += u;
        __syncthreads();
      }
      if (256 + tid < NBK) sbase[256 + tid] = totalA + part[tid] - vB;
    }
    __syncthreads();
#pragma unroll
    for (int k = 0; k < CHUNK / 256; ++k) {
      if (bk[k] >= 0) {
        int pos = sbase[bk[k]] + atomicAdd(&lcur[bk[k]], 1);
        buf[pos] = pk[k];
        barr[pos] = (unsigned short)bk[k];
      }
    }
    __syncthreads();
    for (int i = tid; i < NBK; i += 256)
      if (hist[i] > 0) gbase[i] = i * CAP + atomicAdd(&bcnt[i], hist[i]) - sbase[i];
    __syncthreads();
    for (int j = tid; j < m; j += 256)
      gpairs[gbase[barr[j]] + j] = buf[j];
  } else if (bid < NBSC + NBXB) {
    // ---- xb role ----
    int base = (bid - NBSC) * (256 * XB_BATCH);
    float4 v[XB_BATCH];
#pragma unroll
    for (int k = 0; k < XB_BATCH; ++k) {
      int i = base + k * 256 + tid;
      if (i < NQ) v[k] = ((const float4*)x)[i];
    }
#pragma unroll
    for (int k = 0; k < XB_BATCH; ++k) {
      int i = base + k * 256 + tid;
      if (i < NQ) {
        ushort4 s;
        s.x = f2bf(v[k].x); s.y = f2bf(v[k].y); s.z = f2bf(v[k].z); s.w = f2bf(v[k].w);
        ((ushort4*)xb)[i] = s;
      }
    }
  } else {
    // ---- prep role: combined B in MFMA fragment order ----
    int t3 = (bid - NBSC - NBXB) * 256 + tid;
    if (t3 < 5 * DIM * DIM) {
      int b = t3 / (DIM * DIM);
      int idx = t3 - b * DIM * DIM;   // k*DIM + n
      int k = idx >> 7, n = idx & 127;
      float v;
      if (b == 0)
        v = 0.25f * (Ws[idx] + Ws[DIM * DIM + idx] + Ws[2 * DIM * DIM + idx] + Ws[3 * DIM * DIM + idx]);
      else
        v = 0.25f * Wn[(b - 1) * DIM * DIM + idx];
      int ks = k >> 5, kq = (k >> 3) & 3, j = k & 7;
      int ct = n >> 4, lr = n & 15;
      int lane = kq * 16 + lr;
      Wt[((((b * 4 + ks) * 8) + ct) * 64 + lane) * 8 + j] = f2bf(v);
    }
    if (t3 < DIM)
      biasc[t3] = 0.25f * (bv[t3] + bv[DIM + t3] + bv[2 * DIM + t3] + bv[3 * DIM + t3]);
  }
}

// One block per bucket: LDS count + scan -> exact CSR within padded bucket region.
// ssrc staged through LDS (sbuf) sorted by final position, then written coalesced.
// offs is bucket-strided: 1025 entries per bucket; consumer index = fl + (fl >> 10).
__global__ __launch_bounds__(256) void bfill_kernel(
    const unsigned int* __restrict__ gpairs, const int* __restrict__ bcnt,
    int* __restrict__ offs, int* __restrict__ ssrc) {
  __shared__ int lcnt[BSLOT];
  __shared__ int lofs[BSLOT];
  __shared__ int lcur[BSLOT];
  __shared__ int part[256];
  __shared__ int sbuf[CAP];     // 32 KB staging for coalesced ssrc write
  int b = blockIdx.x;
  int tid = threadIdx.x;
  int base = b * CAP;
  int cntb = bcnt[b];
  int flBase = b << 10;
  int flCount = M_FLAT - flBase; if (flCount > BSLOT) flCount = BSLOT;
  for (int i = tid; i < BSLOT; i += 256) { lcnt[i] = 0; lcur[i] = 0; }
  __syncthreads();
  for (int j = tid; j < cntb; j += 256)
    atomicAdd(&lcnt[gpairs[base + j] >> 17], 1);
  __syncthreads();
  int vals[4]; int s0 = 0;
#pragma unroll
  for (int k = 0; k < 4; ++k) { vals[k] = lcnt[tid * 4 + k]; s0 += vals[k]; }
  part[tid] = s0;
  __syncthreads();
  for (int o = 1; o < 256; o <<= 1) {
    int u = (tid >= o) ? part[tid - o] : 0;
    __syncthreads();
    part[tid] += u;
    __syncthreads();
  }
  int excl = part[tid] - s0;
#pragma unroll
  for (int k = 0; k < 4; ++k) { lofs[tid * 4 + k] = excl; excl += vals[k]; }
  __syncthreads();
  for (int i = tid; i <= flCount; i += 256)
    offs[b * (BSLOT + 1) + i] = base + ((i < BSLOT) ? lofs[i] : cntb);
  for (int j = tid; j < cntb; j += 256) {
    unsigned int p = gpairs[base + j];
    int li = p >> 17;
    int pos = atomicAdd(&lcur[li], 1);
    sbuf[lofs[li] + pos] = (int)(p & 0x1FFFFu);
  }
  __syncthreads();
  for (int j = tid; j < cntb; j += 256)
    ssrc[base + j] = sbuf[j];
}

// One wave per node, ONE relation per dispatch (4-way split: drops the rocprof
// top-5 cut to ~28us so pre/gemm become visible; R7/R9 proved the gather is
// schedule-insensitive so the split costs only launch overhead).
// agg writes are NON-TEMPORAL: write-once data must not evict the gather-hot
// xb lines from L2 (theory: agg's 100MB write stream is what caps xb hit at 33%).
__global__ __launch_bounds__(256) void aggregate_kernel(
    const unsigned int* __restrict__ xb32, const int* __restrict__ ssrc,
    const int* __restrict__ offs, unsigned int* __restrict__ agg32, int r) {
  int lane = threadIdx.x & 63;
  int n = blockIdx.x * 4 + (int)__builtin_amdgcn_readfirstlane(threadIdx.x >> 6);
  if (n >= N_NODES) return;

  int fl = r * N_NODES + n;
  int oidx = fl + (fl >> 10);   // bucket-strided offs index
  int start = __builtin_amdgcn_readfirstlane(offs[oidx]);
  int end = __builtin_amdgcn_readfirstlane(offs[oidx + 1]);
  int c = end - start;

  f32x2 acc = {0.f, 0.f};
  for (int e = start; e < end; e += 8) {
    int m = end - e;   // wave-uniform
    unsigned int v[8];
#pragma unroll
    for (int k = 0; k < 8; ++k) {
      int idx = ssrc[e + ((k < m) ? k : 0)];                 // uniform index
      v[k] = xb32[((unsigned)idx << 6) | (unsigned)lane];    // sgpr-base + voffset
    }
#pragma unroll
    for (int k = 0; k < 8; ++k) {
      unsigned int u = (k < m) ? v[k] : 0u;
      f32x2 d;
      d.x = __uint_as_float(u << 16);          // low bf16
      d.y = __uint_as_float(u & 0xffff0000u);  // high bf16
      acc += d;                                 // v_pk_add_f32
    }
  }
  float inv = __builtin_amdgcn_rcpf((float)(c > 0 ? c : 1));
  float lo = acc.x * inv, hi = acc.y * inv;
  unsigned int packed;
  asm("v_cvt_pk_bf16_f32 %0, %1, %2" : "=v"(packed) : "v"(lo), "v"(hi));
  __builtin_nontemporal_store(packed, &agg32[((size_t)r * N_NODES + n) * 64 + lane]);
}

// Hardcoded 5-slab GEMM, fully unrolled. B slabs LDS-staged; A-fragments
// register-direct from global (non-temporal: read-once) with one-slab-ahead
// double-buffer; out stores non-temporal (write-once).
__global__ __launch_bounds__(256) void gemm_kernel(
    const unsigned short* __restrict__ xb, const unsigned short* __restrict__ Wt,
    const float* __restrict__ biasc, float* __restrict__ out,
    const unsigned short* __restrict__ agg) {
  __shared__ short8 Bs[2048];   // 32 KB: one B slab (4 ks x 8 ct x 64 lanes)
  int tid = threadIdx.x;
  int lane = tid & 63;
  int wv = __builtin_amdgcn_readfirstlane(tid >> 6);
  int bandRow = blockIdx.x * 128 + wv * 32;
  int valid = bandRow < N_NODES;           // wave-uniform (N_NODES % 32 == 0)
  int ldRow = valid ? bandRow : 0;
  int quad = lane >> 4;
  int lr = lane & 15;
  const short8* Bp = (const short8*)Wt;

  float bias8[8];
#pragma unroll
  for (int ct = 0; ct < 8; ++ct) bias8[ct] = biasc[ct * 16 + lr];

  f32x4 zero = {0.f, 0.f, 0.f, 0.f};
  f32x4 acc[2][8];
#pragma unroll
  for (int rt = 0; rt < 2; ++rt)
#pragma unroll
    for (int ct = 0; ct < 8; ++ct) acc[rt][ct] = zero;

  // stage B slab 0 and preload A slab 0 (xb) before the first barrier
#pragma unroll
  for (int p = 0; p < 8; ++p) Bs[p * 256 + tid] = Bp[p * 256 + tid];
  short8 a0c[4], a1c[4];
  {
    const unsigned short* rowp = xb + (size_t)(ldRow + lr) * DIM;
#pragma unroll
    for (int ks = 0; ks < 4; ++ks) {
      int k0 = ks * 32 + quad * 8;
      a0c[ks] = __builtin_nontemporal_load((const short8*)(rowp + k0));
      a1c[ks] = __builtin_nontemporal_load((const short8*)(rowp + 16 * DIM + k0));
    }
  }
  __syncthreads();

#pragma unroll
  for (int bi = 0; bi < 5; ++bi) {
    short8 a0n[4], a1n[4];
    if (bi < 4) {
      // next slab's A source: agg slab bi (slabs 1..4 are agg relations 0..3)
      const unsigned short* rowp = agg + (size_t)bi * N_NODES * DIM + (size_t)(ldRow + lr) * DIM;
#pragma unroll
      for (int ks = 0; ks < 4; ++ks) {
        int k0 = ks * 32 + quad * 8;
        a0n[ks] = __builtin_nontemporal_load((const short8*)(rowp + k0));
        a1n[ks] = __builtin_nontemporal_load((const short8*)(rowp + 16 * DIM + k0));
      }
    }
#pragma unroll
    for (int ks = 0; ks < 4; ++ks) {
#pragma unroll
      for (int ct = 0; ct < 8; ++ct) {
        short8 bf = Bs[(ks * 8 + ct) * 64 + lane];
        acc[0][ct] = __builtin_amdgcn_mfma_f32_16x16x32_bf16(a0c[ks], bf, acc[0][ct], 0, 0, 0);
        acc[1][ct] = __builtin_amdgcn_mfma_f32_16x16x32_bf16(a1c[ks], bf, acc[1][ct], 0, 0, 0);
      }
    }
    if (bi < 4) {
      __syncthreads();   // all waves done reading Bs(bi)
#pragma unroll
      for (int p = 0; p < 8; ++p)
        Bs[p * 256 + tid] = Bp[(size_t)(bi + 1) * 2048 + p * 256 + tid];
      __syncthreads();   // Bs(bi+1) visible
#pragma unroll
      for (int ks = 0; ks < 4; ++ks) { a0c[ks] = a0n[ks]; a1c[ks] = a1n[ks]; }
    }
  }

  if (valid) {
#pragma unroll
    for (int rt = 0; rt < 2; ++rt)
#pragma unroll
      for (int i = 0; i < 4; ++i) {
        int g = bandRow + rt * 16 + quad * 4 + i;
#pragma unroll
        for (int ct = 0; ct < 8; ++ct)
          __builtin_nontemporal_store(acc[rt][ct][i] + bias8[ct],
                                      &out[(size_t)g * DIM + ct * 16 + lr]);
      }
  }
}

extern "C" void kernel_launch(void* const* d_in, const int* in_sizes, int n_in,
                              void* d_out, int out_size, void* d_ws, size_t ws_size,
                              hipStream_t stream) {
  const float* x = (const float*)d_in[0];
  const int* src = (const int*)d_in[1];
  const int* dst = (const int*)d_in[2];
  const float* Wself = (const float*)d_in[3];
  const float* Wneigh = (const float*)d_in[4];
  const float* bv = (const float*)d_in[5];
  float* out = (float*)d_out;

  char* ws = (char*)d_ws;
  size_t off = 0;
  int* bcnt = (int*)(ws + off);        off += 2048;                                    // 391 cursors
  unsigned short* Wt = (unsigned short*)(ws + off);  off += 5 * DIM * DIM * 2;         // 160 KB
  float* biasc = (float*)(ws + off);   off += DIM * 4;
  int* offs = (int*)(ws + off);        off += ((size_t)NBK * (BSLOT + 1) * 4 + 15) & ~15;  // 1.6 MB
  unsigned short* xb = (unsigned short*)(ws + off);  off += (size_t)N_NODES * DIM * 2;  // 25.6 MB
  unsigned int* gpairs = (unsigned int*)(ws + off);  off += (size_t)NBK * CAP * 4;      // 12.8 MB
  int* ssrc = (int*)(ws + off);        off += (size_t)NBK * CAP * 4;                    // 12.8 MB
  unsigned short* agg = (unsigned short*)(ws + off);  // 4 slabs = 102.4 MB

  hipMemsetAsync(bcnt, 0, 2048, stream);
  pre_kernel<<<NBSC + NBXB + NBPREP, 256, 0, stream>>>(src, dst, bcnt, gpairs,
                                                       x, xb, Wself, Wneigh, bv, Wt, biasc);
  bfill_kernel<<<NBK, 256, 0, stream>>>(gpairs, bcnt, offs, ssrc);

  int gAgg = (N_NODES + 3) / 4;       // wave per node
  for (int r = 0; r < NREL; ++r)
    aggregate_kernel<<<gAgg, 256, 0, stream>>>((const unsigned int*)xb, ssrc, offs,
                                               (unsigned int*)agg, r);
  gemm_kernel<<<(N_NODES + 127) / 128, 256, 0, stream>>>(xb, Wt, biasc, out, agg);
}

// Round 12
// 288.523 us; speedup vs baseline: 1.0836x; 1.0836x over previous
//
#include <hip/hip_runtime.h>
#include <hip/hip_bf16.h>
#include <stdint.h>

#define N_NODES 100000
#define DIM 128
#define NREL 4
#define NEDGE 500000
#define M_FLAT (NREL * N_NODES)        // 400000 flat (r,node) slots
#define TOT_E (NREL * NEDGE)           // 2M edges
#define BSLOT 1024                     // flat slots per bucket
#define NBK ((M_FLAT + BSLOT - 1) / BSLOT)   // 391 buckets
#define CAP 8192                       // padded edge capacity per bucket (mean 5120, 43 sigma slack)
#define CHUNK 8192                     // edges per bscatter role-block
#define NBSC ((TOT_E + CHUNK - 1) / CHUNK)            // 245 bscatter blocks
#define NQ (N_NODES * DIM / 4)                        // 3.2M float4 elements for xb
#define XB_BATCH 8
#define NBXB ((NQ + 256 * XB_BATCH - 1) / (256 * XB_BATCH))   // 1563 xb blocks
#define NBPREP ((5 * DIM * DIM + 255) / 256)          // 320 prep blocks

typedef __attribute__((ext_vector_type(8))) short short8;
typedef __attribute__((ext_vector_type(4))) float f32x4;
typedef __attribute__((ext_vector_type(2))) float f32x2;

__device__ __forceinline__ unsigned short f2bf(float f) {
  unsigned int u = __float_as_uint(f);
  u += 0x7fffu + ((u >> 16) & 1u);   // RNE
  return (unsigned short)(u >> 16);
}

// Fused preprocessing, role-split by blockIdx (independent jobs; fusing removes
// two serial dispatches + hides xb/prep under bscatter — R8/R10 measured best).
__global__ __launch_bounds__(256) void pre_kernel(
    const int* __restrict__ src, const int* __restrict__ dst,
    int* __restrict__ bcnt, unsigned int* __restrict__ gpairs,
    const float* __restrict__ x, unsigned short* __restrict__ xb,
    const float* __restrict__ Ws, const float* __restrict__ Wn,
    const float* __restrict__ bv, unsigned short* __restrict__ Wt,
    float* __restrict__ biasc) {
  __shared__ unsigned int buf[CHUNK];
  __shared__ unsigned short barr[CHUNK];
  __shared__ int hist[NBK];
  __shared__ int sbase[NBK];
  __shared__ int lcur[NBK];
  __shared__ int gbase[NBK];
  __shared__ int part[256];
  int bid = blockIdx.x;
  int tid = threadIdx.x;

  if (bid < NBSC) {
    // ---- bscatter role ----
    int base = bid * CHUNK;
    int m = TOT_E - base; if (m > CHUNK) m = CHUNK;
    for (int i = tid; i < NBK; i += 256) { hist[i] = 0; lcur[i] = 0; }
    __syncthreads();
    unsigned int pk[CHUNK / 256];
    int bk[CHUNK / 256];
#pragma unroll
    for (int k = 0; k < CHUNK / 256; ++k) {
      int i = k * 256 + tid;
      int idx = base + i;
      int b = -1; unsigned int p = 0;
      if (i < m) {
        int r = idx / NEDGE;
        int fl = r * N_NODES + dst[idx];
        b = fl >> 10;
        p = ((unsigned int)(fl & (BSLOT - 1)) << 17) | (unsigned int)src[idx];
        atomicAdd(&hist[b], 1);
      }
      pk[k] = p; bk[k] = b;
    }
    __syncthreads();
    // two-pass exclusive scan over hist[0..NBK) (NBK = 391 > 256)
    {
      int vA = hist[tid];
      part[tid] = vA;
      __syncthreads();
      for (int o = 1; o < 256; o <<= 1) {
        int u = (tid >= o) ? part[tid - o] : 0;
        __syncthreads();
        part[tid] += u;
        __syncthreads();
      }
      sbase[tid] = part[tid] - vA;
      int totalA = part[255];
      __syncthreads();
      int vB = (256 + tid < NBK) ? hist[256 + tid] : 0;
      part[tid] = vB;
      __syncthreads();
      for (int o = 1; o < 256; o <<= 1) {
        int u = (tid >= o) ? part[tid - o] : 0;
        __syncthreads();
        part[tid] += u;
        __syncthreads();
      }
      if (256 + tid < NBK) sbase[256 + tid] = totalA + part[tid] - vB;
    }
    __syncthreads();
#pragma unroll
    for (int k = 0; k < CHUNK / 256; ++k) {
      if (bk[k] >= 0) {
        int pos = sbase[bk[k]] + atomicAdd(&lcur[bk[k]], 1);
        buf[pos] = pk[k];
        barr[pos] = (unsigned short)bk[k];
      }
    }
    __syncthreads();
    for (int i = tid; i < NBK; i += 256)
      if (hist[i] > 0) gbase[i] = i * CAP + atomicAdd(&bcnt[i], hist[i]) - sbase[i];
    __syncthreads();
    for (int j = tid; j < m; j += 256)
      gpairs[gbase[barr[j]] + j] = buf[j];
  } else if (bid < NBSC + NBXB) {
    // ---- xb role ----
    int base = (bid - NBSC) * (256 * XB_BATCH);
    float4 v[XB_BATCH];
#pragma unroll
    for (int k = 0; k < XB_BATCH; ++k) {
      int i = base + k * 256 + tid;
      if (i < NQ) v[k] = ((const float4*)x)[i];
    }
#pragma unroll
    for (int k = 0; k < XB_BATCH; ++k) {
      int i = base + k * 256 + tid;
      if (i < NQ) {
        ushort4 s;
        s.x = f2bf(v[k].x); s.y = f2bf(v[k].y); s.z = f2bf(v[k].z); s.w = f2bf(v[k].w);
        ((ushort4*)xb)[i] = s;
      }
    }
  } else {
    // ---- prep role: combined B in MFMA fragment order ----
    int t3 = (bid - NBSC - NBXB) * 256 + tid;
    if (t3 < 5 * DIM * DIM) {
      int b = t3 / (DIM * DIM);
      int idx = t3 - b * DIM * DIM;   // k*DIM + n
      int k = idx >> 7, n = idx & 127;
      float v;
      if (b == 0)
        v = 0.25f * (Ws[idx] + Ws[DIM * DIM + idx] + Ws[2 * DIM * DIM + idx] + Ws[3 * DIM * DIM + idx]);
      else
        v = 0.25f * Wn[(b - 1) * DIM * DIM + idx];
      int ks = k >> 5, kq = (k >> 3) & 3, j = k & 7;
      int ct = n >> 4, lr = n & 15;
      int lane = kq * 16 + lr;
      Wt[((((b * 4 + ks) * 8) + ct) * 64 + lane) * 8 + j] = f2bf(v);
    }
    if (t3 < DIM)
      biasc[t3] = 0.25f * (bv[t3] + bv[DIM + t3] + bv[2 * DIM + t3] + bv[3 * DIM + t3]);
  }
}

// One block per bucket: LDS count + scan -> exact CSR within padded bucket region.
// ssrc staged through LDS (sbuf) sorted by final position, then written coalesced.
// offs is bucket-strided: 1025 entries per bucket; consumer index = fl + (fl >> 10).
__global__ __launch_bounds__(256) void bfill_kernel(
    const unsigned int* __restrict__ gpairs, const int* __restrict__ bcnt,
    int* __restrict__ offs, int* __restrict__ ssrc) {
  __shared__ int lcnt[BSLOT];
  __shared__ int lofs[BSLOT];
  __shared__ int lcur[BSLOT];
  __shared__ int part[256];
  __shared__ int sbuf[CAP];     // 32 KB staging for coalesced ssrc write
  int b = blockIdx.x;
  int tid = threadIdx.x;
  int base = b * CAP;
  int cntb = bcnt[b];
  int flBase = b << 10;
  int flCount = M_FLAT - flBase; if (flCount > BSLOT) flCount = BSLOT;
  for (int i = tid; i < BSLOT; i += 256) { lcnt[i] = 0; lcur[i] = 0; }
  __syncthreads();
  for (int j = tid; j < cntb; j += 256)
    atomicAdd(&lcnt[gpairs[base + j] >> 17], 1);
  __syncthreads();
  int vals[4]; int s0 = 0;
#pragma unroll
  for (int k = 0; k < 4; ++k) { vals[k] = lcnt[tid * 4 + k]; s0 += vals[k]; }
  part[tid] = s0;
  __syncthreads();
  for (int o = 1; o < 256; o <<= 1) {
    int u = (tid >= o) ? part[tid - o] : 0;
    __syncthreads();
    part[tid] += u;
    __syncthreads();
  }
  int excl = part[tid] - s0;
#pragma unroll
  for (int k = 0; k < 4; ++k) { lofs[tid * 4 + k] = excl; excl += vals[k]; }
  __syncthreads();
  for (int i = tid; i <= flCount; i += 256)
    offs[b * (BSLOT + 1) + i] = base + ((i < BSLOT) ? lofs[i] : cntb);
  for (int j = tid; j < cntb; j += 256) {
    unsigned int p = gpairs[base + j];
    int li = p >> 17;
    int pos = atomicAdd(&lcur[li], 1);
    sbuf[lofs[li] + pos] = (int)(p & 0x1FFFFu);
  }
  __syncthreads();
  for (int j = tid; j < cntb; j += 256)
    ssrc[base + j] = sbuf[j];
}

// One wave per node, ALL 4 relations interleaved (fabric-bound at ~4.2 TB/s on
// the random 256B gather; schedule variants R0/R3/R7/R9 all pin at the same
// rate — access-pattern ceiling; NT hints measured as a loss in R11 — removed).
__global__ __launch_bounds__(256) void aggregate_kernel(
    const unsigned int* __restrict__ xb32, const int* __restrict__ ssrc,
    const int* __restrict__ offs, unsigned int* __restrict__ agg32) {
  int lane = threadIdx.x & 63;
  int n = blockIdx.x * 4 + (int)__builtin_amdgcn_readfirstlane(threadIdx.x >> 6);
  if (n >= N_NODES) return;

  int start[NREL], end[NREL];
#pragma unroll
  for (int r = 0; r < NREL; ++r) {
    int fl = r * N_NODES + n;
    int oidx = fl + (fl >> 10);   // bucket-strided offs index
    start[r] = __builtin_amdgcn_readfirstlane(offs[oidx]);
    end[r] = __builtin_amdgcn_readfirstlane(offs[oidx + 1]);
  }

  unsigned int v[NREL][8];
#pragma unroll
  for (int r = 0; r < NREL; ++r) {
    int s = start[r], m = end[r] - s;
#pragma unroll
    for (int k = 0; k < 8; ++k) {
      int ea = (m > 0) ? (s + ((k < m) ? k : (m - 1))) : 0;  // c==0: safe slot 0
      int idx = ssrc[ea];                                    // uniform index
      v[r][k] = xb32[((unsigned)idx << 6) | (unsigned)lane]; // sgpr-base + voffset
    }
  }

  f32x2 acc[NREL];
#pragma unroll
  for (int r = 0; r < NREL; ++r) {
    f32x2 a = {0.f, 0.f};
    int m = end[r] - start[r];
#pragma unroll
    for (int k = 0; k < 8; ++k) {
      unsigned int u = (k < m) ? v[r][k] : 0u;
      f32x2 d;
      d.x = __uint_as_float(u << 16);          // low bf16
      d.y = __uint_as_float(u & 0xffff0000u);  // high bf16
      a += d;                                   // v_pk_add_f32
    }
    acc[r] = a;
  }

  bool anyTail = ((end[0] - start[0]) > 8) | ((end[1] - start[1]) > 8) |
                 ((end[2] - start[2]) > 8) | ((end[3] - start[3]) > 8);
  if (anyTail) {
#pragma unroll
    for (int r = 0; r < NREL; ++r) {
      for (int e = start[r] + 8; e < end[r]; e += 8) {
        int m = end[r] - e;   // > 0, wave-uniform
        unsigned int w[8];
#pragma unroll
        for (int k = 0; k < 8; ++k) {
          int idx = ssrc[e + ((k < m) ? k : 0)];
          w[k] = xb32[((unsigned)idx << 6) | (unsigned)lane];
        }
#pragma unroll
        for (int k = 0; k < 8; ++k) {
          unsigned int u = (k < m) ? w[k] : 0u;
          f32x2 d;
          d.x = __uint_as_float(u << 16);
          d.y = __uint_as_float(u & 0xffff0000u);
          acc[r] += d;
        }
      }
    }
  }

#pragma unroll
  for (int r = 0; r < NREL; ++r) {
    int c = end[r] - start[r];
    float inv = __builtin_amdgcn_rcpf((float)(c > 0 ? c : 1));
    float lo = acc[r].x * inv, hi = acc[r].y * inv;
    unsigned int packed;
    asm("v_cvt_pk_bf16_f32 %0, %1, %2" : "=v"(packed) : "v"(lo), "v"(hi));
    agg32[((size_t)r * N_NODES + n) * 64 + lane] = packed;
  }
}

// 64-row-block GEMM (one 16-row band per wave): grid 782 -> 1563 blocks,
// 32 KB LDS -> ~5 resident blocks/CU (20 waves, 5 independent barrier domains)
// vs R11's 3 blocks/12 waves at MfmaUtil 10% / Occupancy 18.6%. B slabs
// LDS-staged; A-fragments register-direct with one-slab-ahead double-buffer.
// NT hints removed (R11: net loss). No early return (barrier deadlock).
__global__ __launch_bounds__(256) void gemm_kernel(
    const unsigned short* __restrict__ xb, const unsigned short* __restrict__ Wt,
    const float* __restrict__ biasc, float* __restrict__ out,
    const unsigned short* __restrict__ agg) {
  __shared__ short8 Bs[2048];   // 32 KB: one B slab (4 ks x 8 ct x 64 lanes)
  int tid = threadIdx.x;
  int lane = tid & 63;
  int wv = __builtin_amdgcn_readfirstlane(tid >> 6);
  int bandRow = blockIdx.x * 64 + wv * 16;
  int valid = bandRow < N_NODES;           // wave-uniform (N_NODES % 16 == 0)
  int ldRow = valid ? bandRow : 0;
  int quad = lane >> 4;
  int lr = lane & 15;
  const short8* Bp = (const short8*)Wt;

  float bias8[8];
#pragma unroll
  for (int ct = 0; ct < 8; ++ct) bias8[ct] = biasc[ct * 16 + lr];

  f32x4 zero = {0.f, 0.f, 0.f, 0.f};
  f32x4 acc[8];
#pragma unroll
  for (int ct = 0; ct < 8; ++ct) acc[ct] = zero;

  // stage B slab 0 and preload A slab 0 (xb) before the first barrier
#pragma unroll
  for (int p = 0; p < 8; ++p) Bs[p * 256 + tid] = Bp[p * 256 + tid];
  short8 ac[4];
  {
    const unsigned short* rowp = xb + (size_t)(ldRow + lr) * DIM;
#pragma unroll
    for (int ks = 0; ks < 4; ++ks)
      ac[ks] = *(const short8*)(rowp + ks * 32 + quad * 8);
  }
  __syncthreads();

#pragma unroll
  for (int bi = 0; bi < 5; ++bi) {
    short8 an[4];
    if (bi < 4) {
      // next slab's A source: agg slab bi (slabs 1..4 are agg relations 0..3)
      const unsigned short* rowp = agg + (size_t)bi * N_NODES * DIM + (size_t)(ldRow + lr) * DIM;
#pragma unroll
      for (int ks = 0; ks < 4; ++ks)
        an[ks] = *(const short8*)(rowp + ks * 32 + quad * 8);
    }
#pragma unroll
    for (int ks = 0; ks < 4; ++ks) {
#pragma unroll
      for (int ct = 0; ct < 8; ++ct) {
        short8 bf = Bs[(ks * 8 + ct) * 64 + lane];
        acc[ct] = __builtin_amdgcn_mfma_f32_16x16x32_bf16(ac[ks], bf, acc[ct], 0, 0, 0);
      }
    }
    if (bi < 4) {
      __syncthreads();   // all waves done reading Bs(bi)
#pragma unroll
      for (int p = 0; p < 8; ++p)
        Bs[p * 256 + tid] = Bp[(size_t)(bi + 1) * 2048 + p * 256 + tid];
      __syncthreads();   // Bs(bi+1) visible
#pragma unroll
      for (int ks = 0; ks < 4; ++ks) ac[ks] = an[ks];
    }
  }

  if (valid) {
#pragma unroll
    for (int i = 0; i < 4; ++i) {
      int g = bandRow + quad * 4 + i;
#pragma unroll
      for (int ct = 0; ct < 8; ++ct)
        out[(size_t)g * DIM + ct * 16 + lr] = acc[ct][i] + bias8[ct];
    }
  }
}

extern "C" void kernel_launch(void* const* d_in, const int* in_sizes, int n_in,
                              void* d_out, int out_size, void* d_ws, size_t ws_size,
                              hipStream_t stream) {
  const float* x = (const float*)d_in[0];
  const int* src = (const int*)d_in[1];
  const int* dst = (const int*)d_in[2];
  const float* Wself = (const float*)d_in[3];
  const float* Wneigh = (const float*)d_in[4];
  const float* bv = (const float*)d_in[5];
  float* out = (float*)d_out;

  char* ws = (char*)d_ws;
  size_t off = 0;
  int* bcnt = (int*)(ws + off);        off += 2048;                                    // 391 cursors
  unsigned short* Wt = (unsigned short*)(ws + off);  off += 5 * DIM * DIM * 2;         // 160 KB
  float* biasc = (float*)(ws + off);   off += DIM * 4;
  int* offs = (int*)(ws + off);        off += ((size_t)NBK * (BSLOT + 1) * 4 + 15) & ~15;  // 1.6 MB
  unsigned short* xb = (unsigned short*)(ws + off);  off += (size_t)N_NODES * DIM * 2;  // 25.6 MB
  unsigned int* gpairs = (unsigned int*)(ws + off);  off += (size_t)NBK * CAP * 4;      // 12.8 MB
  int* ssrc = (int*)(ws + off);        off += (size_t)NBK * CAP * 4;                    // 12.8 MB
  unsigned short* agg = (unsigned short*)(ws + off);  // 4 slabs = 102.4 MB

  hipMemsetAsync(bcnt, 0, 2048, stream);
  pre_kernel<<<NBSC + NBXB + NBPREP, 256, 0, stream>>>(src, dst, bcnt, gpairs,
                                                       x, xb, Wself, Wneigh, bv, Wt, biasc);
  bfill_kernel<<<NBK, 256, 0, stream>>>(gpairs, bcnt, offs, ssrc);
  aggregate_kernel<<<(N_NODES + 3) / 4, 256, 0, stream>>>((const unsigned int*)xb, ssrc,
                                                          offs, (unsigned int*)agg);
  gemm_kernel<<<(N_NODES + 63) / 64, 256, 0, stream>>>(xb, Wt, biasc, out, agg);
}

// Round 13
// 280.523 us; speedup vs baseline: 1.1145x; 1.0285x over previous
//
#include <hip/hip_runtime.h>
#include <hip/hip_bf16.h>
#include <stdint.h>

#define N_NODES 100000
#define DIM 128
#define NREL 4
#define NEDGE 500000
#define M_FLAT (NREL * N_NODES)        // 400000 flat (r,node) slots
#define TOT_E (NREL * NEDGE)           // 2M edges
#define BSLOT 1024                     // flat slots per bucket
#define NBK ((M_FLAT + BSLOT - 1) / BSLOT)   // 391 buckets
#define CAP 8192                       // padded edge capacity per bucket (mean 5120, 43 sigma slack)
#define CHUNK 4096                     // edges per bscatter role-block (31.4KB LDS -> 5 blocks/CU)
#define NBSC ((TOT_E + CHUNK - 1) / CHUNK)            // 489 bscatter blocks
#define NQ (N_NODES * DIM / 4)                        // 3.2M float4 elements for xb
#define XB_BATCH 8
#define NBXB ((NQ + 256 * XB_BATCH - 1) / (256 * XB_BATCH))   // 1563 xb blocks
#define NBPREP ((5 * DIM * DIM + 255) / 256)          // 320 prep blocks

typedef __attribute__((ext_vector_type(8))) short short8;
typedef __attribute__((ext_vector_type(4))) float f32x4;
typedef __attribute__((ext_vector_type(2))) float f32x2;

__device__ __forceinline__ unsigned short f2bf(float f) {
  unsigned int u = __float_as_uint(f);
  u += 0x7fffu + ((u >> 16) & 1u);   // RNE
  return (unsigned short)(u >> 16);
}

// Fused preprocessing, role-split by blockIdx. CHUNK=4096 keeps static LDS at
// ~31.4KB so ALL roles run 5 blocks/CU (R8-R12 ran 56KB -> 2 blocks/CU, which
// starved the BW-bound xb role; R7 bundled CHUNK=8192 with fusion untested).
__global__ __launch_bounds__(256) void pre_kernel(
    const int* __restrict__ src, const int* __restrict__ dst,
    int* __restrict__ bcnt, unsigned int* __restrict__ gpairs,
    const float* __restrict__ x, unsigned short* __restrict__ xb,
    const float* __restrict__ Ws, const float* __restrict__ Wn,
    const float* __restrict__ bv, unsigned short* __restrict__ Wt,
    float* __restrict__ biasc) {
  __shared__ unsigned int buf[CHUNK];        // 16 KB
  __shared__ unsigned short barr[CHUNK];     // 8 KB
  __shared__ int hist[NBK];                  // 1.6 KB
  __shared__ int sbase[NBK];
  __shared__ int lcur[NBK];
  __shared__ int gbase[NBK];
  __shared__ int part[256];                  // 1 KB
  int bid = blockIdx.x;
  int tid = threadIdx.x;

  if (bid < NBSC) {
    // ---- bscatter role ----
    int base = bid * CHUNK;
    int m = TOT_E - base; if (m > CHUNK) m = CHUNK;
    for (int i = tid; i < NBK; i += 256) { hist[i] = 0; lcur[i] = 0; }
    __syncthreads();
    unsigned int pk[CHUNK / 256];
    int bk[CHUNK / 256];
#pragma unroll
    for (int k = 0; k < CHUNK / 256; ++k) {
      int i = k * 256 + tid;
      int idx = base + i;
      int b = -1; unsigned int p = 0;
      if (i < m) {
        int r = idx / NEDGE;
        int fl = r * N_NODES + dst[idx];
        b = fl >> 10;
        p = ((unsigned int)(fl & (BSLOT - 1)) << 17) | (unsigned int)src[idx];
        atomicAdd(&hist[b], 1);
      }
      pk[k] = p; bk[k] = b;
    }
    __syncthreads();
    // two-pass exclusive scan over hist[0..NBK) (NBK = 391 > 256)
    {
      int vA = hist[tid];
      part[tid] = vA;
      __syncthreads();
      for (int o = 1; o < 256; o <<= 1) {
        int u = (tid >= o) ? part[tid - o] : 0;
        __syncthreads();
        part[tid] += u;
        __syncthreads();
      }
      sbase[tid] = part[tid] - vA;
      int totalA = part[255];
      __syncthreads();
      int vB = (256 + tid < NBK) ? hist[256 + tid] : 0;
      part[tid] = vB;
      __syncthreads();
      for (int o = 1; o < 256; o <<= 1) {
        int u = (tid >= o) ? part[tid - o] : 0;
        __syncthreads();
        part[tid] += u;
        __syncthreads();
      }
      if (256 + tid < NBK) sbase[256 + tid] = totalA + part[tid] - vB;
    }
    __syncthreads();
#pragma unroll
    for (int k = 0; k < CHUNK / 256; ++k) {
      if (bk[k] >= 0) {
        int pos = sbase[bk[k]] + atomicAdd(&lcur[bk[k]], 1);
        buf[pos] = pk[k];
        barr[pos] = (unsigned short)bk[k];
      }
    }
    __syncthreads();
    for (int i = tid; i < NBK; i += 256)
      if (hist[i] > 0) gbase[i] = i * CAP + atomicAdd(&bcnt[i], hist[i]) - sbase[i];
    __syncthreads();
    for (int j = tid; j < m; j += 256)
      gpairs[gbase[barr[j]] + j] = buf[j];
  } else if (bid < NBSC + NBXB) {
    // ---- xb role ----
    int base = (bid - NBSC) * (256 * XB_BATCH);
    float4 v[XB_BATCH];
#pragma unroll
    for (int k = 0; k < XB_BATCH; ++k) {
      int i = base + k * 256 + tid;
      if (i < NQ) v[k] = ((const float4*)x)[i];
    }
#pragma unroll
    for (int k = 0; k < XB_BATCH; ++k) {
      int i = base + k * 256 + tid;
      if (i < NQ) {
        ushort4 s;
        s.x = f2bf(v[k].x); s.y = f2bf(v[k].y); s.z = f2bf(v[k].z); s.w = f2bf(v[k].w);
        ((ushort4*)xb)[i] = s;
      }
    }
  } else {
    // ---- prep role: combined B in MFMA fragment order ----
    int t3 = (bid - NBSC - NBXB) * 256 + tid;
    if (t3 < 5 * DIM * DIM) {
      int b = t3 / (DIM * DIM);
      int idx = t3 - b * DIM * DIM;   // k*DIM + n
      int k = idx >> 7, n = idx & 127;
      float v;
      if (b == 0)
        v = 0.25f * (Ws[idx] + Ws[DIM * DIM + idx] + Ws[2 * DIM * DIM + idx] + Ws[3 * DIM * DIM + idx]);
      else
        v = 0.25f * Wn[(b - 1) * DIM * DIM + idx];
      int ks = k >> 5, kq = (k >> 3) & 3, j = k & 7;
      int ct = n >> 4, lr = n & 15;
      int lane = kq * 16 + lr;
      Wt[((((b * 4 + ks) * 8) + ct) * 64 + lane) * 8 + j] = f2bf(v);
    }
    if (t3 < DIM)
      biasc[t3] = 0.25f * (bv[t3] + bv[DIM + t3] + bv[2 * DIM + t3] + bv[3 * DIM + t3]);
  }
}

// One 512-thread block per bucket. Pairs are register-cached (gpairs read ONCE,
// was twice = 16MB), scan phases halved vs 256 threads, lofs u16. LDS ~44KB ->
// 3 blocks/CU (24 waves) vs old 57KB/2 blocks. ssrc staged via sbuf, written
// coalesced. offs bucket-strided: consumer index = fl + (fl >> 10).
__global__ __launch_bounds__(512) void bfill_kernel(
    const unsigned int* __restrict__ gpairs, const int* __restrict__ bcnt,
    int* __restrict__ offs, int* __restrict__ ssrc) {
  __shared__ int lcnt[BSLOT];              // 4 KB
  __shared__ unsigned short lofs[BSLOT];   // 2 KB
  __shared__ int lcur[BSLOT];              // 4 KB
  __shared__ int part[512];                // 2 KB
  __shared__ int sbuf[CAP];                // 32 KB
  int b = blockIdx.x;
  int tid = threadIdx.x;
  int base = b * CAP;
  int cntb = bcnt[b];
  int flBase = b << 10;
  int flCount = M_FLAT - flBase; if (flCount > BSLOT) flCount = BSLOT;
  for (int i = tid; i < BSLOT; i += 512) { lcnt[i] = 0; lcur[i] = 0; }
  __syncthreads();
  // load pairs once into registers (CAP/512 = 16 per thread, coalesced)
  unsigned int pk[CAP / 512];
#pragma unroll
  for (int k = 0; k < CAP / 512; ++k) {
    int j = k * 512 + tid;
    pk[k] = (j < cntb) ? gpairs[base + j] : 0u;
  }
#pragma unroll
  for (int k = 0; k < CAP / 512; ++k) {
    int j = k * 512 + tid;
    if (j < cntb) atomicAdd(&lcnt[pk[k] >> 17], 1);
  }
  __syncthreads();
  int vals[2]; int s0 = 0;
#pragma unroll
  for (int k = 0; k < 2; ++k) { vals[k] = lcnt[tid * 2 + k]; s0 += vals[k]; }
  part[tid] = s0;
  __syncthreads();
  for (int o = 1; o < 512; o <<= 1) {
    int u = (tid >= o) ? part[tid - o] : 0;
    __syncthreads();
    part[tid] += u;
    __syncthreads();
  }
  int excl = part[tid] - s0;
  lofs[tid * 2] = (unsigned short)excl;
  lofs[tid * 2 + 1] = (unsigned short)(excl + vals[0]);
  __syncthreads();
  for (int i = tid; i <= flCount; i += 512)
    offs[b * (BSLOT + 1) + i] = base + ((i < BSLOT) ? (int)lofs[i] : cntb);
#pragma unroll
  for (int k = 0; k < CAP / 512; ++k) {
    int j = k * 512 + tid;
    if (j < cntb) {
      int li = pk[k] >> 17;
      int pos = atomicAdd(&lcur[li], 1);
      sbuf[(int)lofs[li] + pos] = (int)(pk[k] & 0x1FFFFu);
    }
  }
  __syncthreads();
  for (int j = tid; j < cntb; j += 512)
    ssrc[base + j] = sbuf[j];
}

// One wave per node, ALL 4 relations interleaved (fabric-bound at ~4.2 TB/s on
// the random 256B gather — six consecutive identical profiles; access-pattern
// ceiling, kept as-is).
__global__ __launch_bounds__(256) void aggregate_kernel(
    const unsigned int* __restrict__ xb32, const int* __restrict__ ssrc,
    const int* __restrict__ offs, unsigned int* __restrict__ agg32) {
  int lane = threadIdx.x & 63;
  int n = blockIdx.x * 4 + (int)__builtin_amdgcn_readfirstlane(threadIdx.x >> 6);
  if (n >= N_NODES) return;

  int start[NREL], end[NREL];
#pragma unroll
  for (int r = 0; r < NREL; ++r) {
    int fl = r * N_NODES + n;
    int oidx = fl + (fl >> 10);   // bucket-strided offs index
    start[r] = __builtin_amdgcn_readfirstlane(offs[oidx]);
    end[r] = __builtin_amdgcn_readfirstlane(offs[oidx + 1]);
  }

  unsigned int v[NREL][8];
#pragma unroll
  for (int r = 0; r < NREL; ++r) {
    int s = start[r], m = end[r] - s;
#pragma unroll
    for (int k = 0; k < 8; ++k) {
      int ea = (m > 0) ? (s + ((k < m) ? k : (m - 1))) : 0;  // c==0: safe slot 0
      int idx = ssrc[ea];                                    // uniform index
      v[r][k] = xb32[((unsigned)idx << 6) | (unsigned)lane]; // sgpr-base + voffset
    }
  }

  f32x2 acc[NREL];
#pragma unroll
  for (int r = 0; r < NREL; ++r) {
    f32x2 a = {0.f, 0.f};
    int m = end[r] - start[r];
#pragma unroll
    for (int k = 0; k < 8; ++k) {
      unsigned int u = (k < m) ? v[r][k] : 0u;
      f32x2 d;
      d.x = __uint_as_float(u << 16);          // low bf16
      d.y = __uint_as_float(u & 0xffff0000u);  // high bf16
      a += d;                                   // v_pk_add_f32
    }
    acc[r] = a;
  }

  bool anyTail = ((end[0] - start[0]) > 8) | ((end[1] - start[1]) > 8) |
                 ((end[2] - start[2]) > 8) | ((end[3] - start[3]) > 8);
  if (anyTail) {
#pragma unroll
    for (int r = 0; r < NREL; ++r) {
      for (int e = start[r] + 8; e < end[r]; e += 8) {
        int m = end[r] - e;   // > 0, wave-uniform
        unsigned int w[8];
#pragma unroll
        for (int k = 0; k < 8; ++k) {
          int idx = ssrc[e + ((k < m) ? k : 0)];
          w[k] = xb32[((unsigned)idx << 6) | (unsigned)lane];
        }
#pragma unroll
        for (int k = 0; k < 8; ++k) {
          unsigned int u = (k < m) ? w[k] : 0u;
          f32x2 d;
          d.x = __uint_as_float(u << 16);
          d.y = __uint_as_float(u & 0xffff0000u);
          acc[r] += d;
        }
      }
    }
  }

#pragma unroll
  for (int r = 0; r < NREL; ++r) {
    int c = end[r] - start[r];
    float inv = __builtin_amdgcn_rcpf((float)(c > 0 ? c : 1));
    float lo = acc[r].x * inv, hi = acc[r].y * inv;
    unsigned int packed;
    asm("v_cvt_pk_bf16_f32 %0, %1, %2" : "=v"(packed) : "v"(lo), "v"(hi));
    agg32[((size_t)r * N_NODES + n) * 64 + lane] = packed;
  }
}

// 64-row-block GEMM (one 16-row band per wave): 1563 blocks, 32 KB LDS ->
// ~5 resident blocks/CU. B slabs LDS-staged; A-fragments register-direct from
// global with one-slab-ahead double-buffer. No early return (barrier deadlock).
__global__ __launch_bounds__(256) void gemm_kernel(
    const unsigned short* __restrict__ xb, const unsigned short* __restrict__ Wt,
    const float* __restrict__ biasc, float* __restrict__ out,
    const unsigned short* __restrict__ agg) {
  __shared__ short8 Bs[2048];   // 32 KB: one B slab (4 ks x 8 ct x 64 lanes)
  int tid = threadIdx.x;
  int lane = tid & 63;
  int wv = __builtin_amdgcn_readfirstlane(tid >> 6);
  int bandRow = blockIdx.x * 64 + wv * 16;
  int valid = bandRow < N_NODES;           // wave-uniform (N_NODES % 16 == 0)
  int ldRow = valid ? bandRow : 0;
  int quad = lane >> 4;
  int lr = lane & 15;
  const short8* Bp = (const short8*)Wt;

  float bias8[8];
#pragma unroll
  for (int ct = 0; ct < 8; ++ct) bias8[ct] = biasc[ct * 16 + lr];

  f32x4 zero = {0.f, 0.f, 0.f, 0.f};
  f32x4 acc[8];
#pragma unroll
  for (int ct = 0; ct < 8; ++ct) acc[ct] = zero;

  // stage B slab 0 and preload A slab 0 (xb) before the first barrier
#pragma unroll
  for (int p = 0; p < 8; ++p) Bs[p * 256 + tid] = Bp[p * 256 + tid];
  short8 ac[4];
  {
    const unsigned short* rowp = xb + (size_t)(ldRow + lr) * DIM;
#pragma unroll
    for (int ks = 0; ks < 4; ++ks)
      ac[ks] = *(const short8*)(rowp + ks * 32 + quad * 8);
  }
  __syncthreads();

#pragma unroll
  for (int bi = 0; bi < 5; ++bi) {
    short8 an[4];
    if (bi < 4) {
      // next slab's A source: agg slab bi (slabs 1..4 are agg relations 0..3)
      const unsigned short* rowp = agg + (size_t)bi * N_NODES * DIM + (size_t)(ldRow + lr) * DIM;
#pragma unroll
      for (int ks = 0; ks < 4; ++ks)
        an[ks] = *(const short8*)(rowp + ks * 32 + quad * 8);
    }
#pragma unroll
    for (int ks = 0; ks < 4; ++ks) {
#pragma unroll
      for (int ct = 0; ct < 8; ++ct) {
        short8 bf = Bs[(ks * 8 + ct) * 64 + lane];
        acc[ct] = __builtin_amdgcn_mfma_f32_16x16x32_bf16(ac[ks], bf, acc[ct], 0, 0, 0);
      }
    }
    if (bi < 4) {
      __syncthreads();   // all waves done reading Bs(bi)
#pragma unroll
      for (int p = 0; p < 8; ++p)
        Bs[p * 256 + tid] = Bp[(size_t)(bi + 1) * 2048 + p * 256 + tid];
      __syncthreads();   // Bs(bi+1) visible
#pragma unroll
      for (int ks = 0; ks < 4; ++ks) ac[ks] = an[ks];
    }
  }

  if (valid) {
#pragma unroll
    for (int i = 0; i < 4; ++i) {
      int g = bandRow + quad * 4 + i;
#pragma unroll
      for (int ct = 0; ct < 8; ++ct)
        out[(size_t)g * DIM + ct * 16 + lr] = acc[ct][i] + bias8[ct];
    }
  }
}

extern "C" void kernel_launch(void* const* d_in, const int* in_sizes, int n_in,
                              void* d_out, int out_size, void* d_ws, size_t ws_size,
                              hipStream_t stream) {
  const float* x = (const float*)d_in[0];
  const int* src = (const int*)d_in[1];
  const int* dst = (const int*)d_in[2];
  const float* Wself = (const float*)d_in[3];
  const float* Wneigh = (const float*)d_in[4];
  const float* bv = (const float*)d_in[5];
  float* out = (float*)d_out;

  char* ws = (char*)d_ws;
  size_t off = 0;
  int* bcnt = (int*)(ws + off);        off += 2048;                                    // 391 cursors
  unsigned short* Wt = (unsigned short*)(ws + off);  off += 5 * DIM * DIM * 2;         // 160 KB
  float* biasc = (float*)(ws + off);   off += DIM * 4;
  int* offs = (int*)(ws + off);        off += ((size_t)NBK * (BSLOT + 1) * 4 + 15) & ~15;  // 1.6 MB
  unsigned short* xb = (unsigned short*)(ws + off);  off += (size_t)N_NODES * DIM * 2;  // 25.6 MB
  unsigned int* gpairs = (unsigned int*)(ws + off);  off += (size_t)NBK * CAP * 4;      // 12.8 MB
  int* ssrc = (int*)(ws + off);        off += (size_t)NBK * CAP * 4;                    // 12.8 MB
  unsigned short* agg = (unsigned short*)(ws + off);  // 4 slabs = 102.4 MB

  hipMemsetAsync(bcnt, 0, 2048, stream);
  pre_kernel<<<NBSC + NBXB + NBPREP, 256, 0, stream>>>(src, dst, bcnt, gpairs,
                                                       x, xb, Wself, Wneigh, bv, Wt, biasc);
  bfill_kernel<<<NBK, 512, 0, stream>>>(gpairs, bcnt, offs, ssrc);
  aggregate_kernel<<<(N_NODES + 3) / 4, 256, 0, stream>>>((const unsigned int*)xb, ssrc,
                                                          offs, (unsigned int*)agg);
  gemm_kernel<<<(N_NODES + 63) / 64, 256, 0, stream>>>(xb, Wt, biasc, out, agg);
}